// Round 9
// baseline (100.414 us; speedup 1.0000x reference)
//
#include <hip/hip_runtime.h>
#include <stdint.h>

#define T_LEN 8192
#define NSTEP 8190   // T - 2 interior samples
#define NB 16
#define NCH 256

// ---------------- threefry2x32 (exact JAX cipher) ----------------
__device__ __forceinline__ uint32_t rotl32(uint32_t v, int r) {
  return (v << r) | (v >> (32 - r));
}

__device__ __forceinline__ void tf2x32(uint32_t k0, uint32_t k1, uint32_t x0, uint32_t x1,
                                       uint32_t& o0, uint32_t& o1) {
  uint32_t ks2 = k0 ^ k1 ^ 0x1BD11BDAu;
  x0 += k0; x1 += k1;
#define RR(r) { x0 += x1; x1 = rotl32(x1, (r)); x1 ^= x0; }
  RR(13) RR(15) RR(26) RR(6)   x0 += k1;  x1 += ks2 + 1u;
  RR(17) RR(29) RR(16) RR(24)  x0 += ks2; x1 += k0 + 2u;
  RR(13) RR(15) RR(26) RR(6)   x0 += k0;  x1 += k1 + 3u;
  RR(17) RR(29) RR(16) RR(24)  x0 += k1;  x1 += ks2 + 4u;
  RR(13) RR(15) RR(26) RR(6)   x0 += ks2; x1 += k0 + 5u;
#undef RR
  o0 = x0; o1 = x1;
}

// ---------------- K1: per-step categorical decisions (VERIFIED r3) ----------
// PARTITIONABLE threefry semantics (JAX >= 0.4.36 default):
//   split(key, n)[i]          = full cipher pair threefry2x32(key, (hi32(i), lo32(i)))
//   random_bits(key,32,(m,))  = bits1 ^ bits2 of cipher(key, (0, c)), c = 0..m-1
// Record BOTH possible decisions: n (normal row), sp (special row (2,1)),
// packed as byte n | (sp<<2).
__global__ __launch_bounds__(256) void k_decide(const float* __restrict__ probs,
                                                uint8_t* __restrict__ dec) {
  int j = blockIdx.x * 256 + threadIdx.x;
  int b = blockIdx.y;
  if (j >= NSTEP) return;

  uint32_t kb0, kb1;
  tf2x32(0u, 42u, 0u, (uint32_t)b, kb0, kb1);      // split(key(42),16)[b]
  uint32_t s0, s1;
  tf2x32(kb0, kb1, 0u, (uint32_t)j, s0, s1);       // split(kb,8190)[j]

  uint32_t bits[3];
  {
    uint32_t y0, y1;
    tf2x32(s0, s1, 0u, 0u, y0, y1); bits[0] = y0 ^ y1;
    tf2x32(s0, s1, 0u, 1u, y0, y1); bits[1] = y0 ^ y1;
    tf2x32(s0, s1, 0u, 2u, y0, y1); bits[2] = y0 ^ y1;
  }

  double g[3];
#pragma unroll
  for (int c = 0; c < 3; ++c) {
    uint32_t k = bits[c] >> 9;                            // 23-bit mantissa sample
    float u = k ? (float)k * 0x1p-23f : 1.17549435e-38f;  // exact JAX uniform value
    g[c] = -log(-log((double)u));
  }

  double lp = log((double)probs[0]);
  double ls = log((double)probs[1]);
  double l1 = log((double)probs[2 * 9 + 1 * 3 + 1]);
  double l2 = log((double)probs[2 * 9 + 1 * 3 + 2]);

  double v0 = lp + g[0], v1 = ls + g[1], v2 = lp + g[2];
  int n = 0; double best = v0;
  if (v1 > best) { n = 1; best = v1; }
  if (v2 > best) { n = 2; }
  int sp = (l1 + g[1] >= l2 + g[2]) ? 1 : 2;

  dec[b * NSTEP + j] = (uint8_t)(n | (sp << 2));
}

// ---------------- K2: parallel Markov scan -> delta bytes (VERIFIED r4) ----
// State u = p2*3 + p1 in [0,9). Step: j = (u==7) ? spec : norm; u' = (u%3)*3 + j.
// Output: dbuf[b][t] = j in {0,1,2}; gather source = t + j - 1.
__device__ __forceinline__ uint64_t compose_map(uint64_t f, uint64_t g) {
  uint64_t r = 0;
#pragma unroll
  for (int st = 0; st < 9; ++st) {
    uint32_t fs = (uint32_t)((f >> (4 * st)) & 15u);
    uint32_t gs = (uint32_t)((g >> (4 * fs)) & 15u);
    r |= ((uint64_t)gs) << (4 * st);
  }
  return r;
}

__device__ __forceinline__ uint64_t shflup64(uint64_t v, int delta) {
  int lo = __shfl_up((int)(uint32_t)v, delta, 64);
  int hi = __shfl_up((int)(uint32_t)(v >> 32), delta, 64);
  return (((uint64_t)(uint32_t)hi) << 32) | (uint32_t)lo;
}

#define IDENT_MAP 0x876543210ull

__global__ __launch_bounds__(256) void k_scan(const uint8_t* __restrict__ dec,
                                              uint8_t* __restrict__ dbuf) {
  int b = blockIdx.x;
  int tid = threadIdx.x;
  int lane = tid & 63, wave = tid >> 6;
  int begin = tid * 32;
  const uint8_t* row = dec + b * NSTEP;

  // phase 1: build this chunk's 9-state map
  uint64_t M = IDENT_MAP;
#pragma unroll
  for (int t = 0; t < 32; ++t) {
    int step = begin + t;
    if (step < NSTEP) {
      int d = row[step];
      uint32_t n = d & 3u, s = (d >> 2) & 3u;
      uint64_t Mn = 0;
#pragma unroll
      for (int st = 0; st < 9; ++st) {
        uint32_t u = (uint32_t)((M >> (4 * st)) & 15u);
        uint32_t div3 = (u * 11u) >> 5;          // u/3 for u<9
        uint32_t p1 = u - 3u * div3;
        uint32_t jj = (u == 7u) ? s : n;
        Mn |= ((uint64_t)(p1 * 3u + jj)) << (4 * st);
      }
      M = Mn;
    }
  }

  // phase 2a: wave-inclusive scan
  uint64_t I = M;
#pragma unroll
  for (int off = 1; off < 64; off <<= 1) {
    uint64_t Mp = shflup64(I, off);
    uint64_t c = compose_map(Mp, I);
    I = (lane >= off) ? c : I;
  }

  __shared__ uint64_t wmap[4];
  if (lane == 63) wmap[wave] = I;
  __syncthreads();

  // phase 2b: exclusive prefix
  uint64_t W = IDENT_MAP;
  for (int w = 0; w < wave; ++w) W = compose_map(W, wmap[w]);
  uint64_t E = shflup64(I, 1);
  if (lane == 0) E = IDENT_MAP;
  uint64_t X = compose_map(W, E);

  int state = (int)((X >> (4 * 4)) & 15u);  // applied to initial chain state (1,1)=4

  // phase 3: replay chunk, emit delta bytes dbuf[b][step+1] = j
  uint8_t* orow = dbuf + b * T_LEN;
#pragma unroll
  for (int t = 0; t < 32; ++t) {
    int step = begin + t;
    if (step < NSTEP) {
      int d = row[step];
      uint32_t n = d & 3u, s = (d >> 2) & 3u;
      uint32_t jj = (state == 7) ? s : n;
      uint32_t div3 = ((uint32_t)state * 11u) >> 5;
      uint32_t p1 = (uint32_t)state - 3u * div3;
      state = (int)(p1 * 3u + jj);
      orow[step + 1] = (uint8_t)jj;
    }
  }
  if (tid == 0) { orow[0] = 1; orow[T_LEN - 1] = 1; }   // forced j=1 -> src=t
}

// ---------------- K3: fat shift-select gather (64 B out / thread) ----------
// out[b,i,t] = x[b,i,t+d-1], d in {0,1,2}. Each thread covers 16 consecutive
// t: 1 uint4 delta load (16 bytes of deltas), 4 contiguous float4 x-loads,
// 2 scalar halos (clamped at array ends; forced d=1 there => never selected),
// 4 nt float4 stores. All selects use compile-time window indices (no
// scratch). 8192 blocks, ~40 VGPR.
typedef float f32x4 __attribute__((ext_vector_type(4)));

__global__ __launch_bounds__(256) void k_gather(const float* __restrict__ x,
                                                const uint8_t* __restrict__ dbuf,
                                                float* __restrict__ out) {
  const int bid = blockIdx.x;
  const int tc = bid & 1;            // t-half (fastest -> contiguous sweep)
  const int i  = (bid >> 1) & 255;   // channel
  const int b  = bid >> 9;           // batch
  const int t0 = tc * 4096 + threadIdx.x * 16;

  const uint4 du = *(const uint4*)(dbuf + b * T_LEN + t0);   // 16 delta bytes
  const uint32_t dw[4] = { du.x, du.y, du.z, du.w };

  const float* __restrict__ xr = x + ((size_t)(b * NCH + i)) * T_LEN;
  const int tl = (t0 == 0) ? 0 : t0 - 1;                      // never selected at edge
  const int tr = (t0 + 16 >= T_LEN) ? (T_LEN - 1) : t0 + 16;  // never selected at edge

  // window w[k] = x[t0 - 1 + k], k = 0..17
  float w[18];
  w[0] = xr[tl];
  *(float4*)(w + 1)  = *(const float4*)(xr + t0);
  *(float4*)(w + 5)  = *(const float4*)(xr + t0 + 4);
  *(float4*)(w + 9)  = *(const float4*)(xr + t0 + 8);
  *(float4*)(w + 13) = *(const float4*)(xr + t0 + 12);
  w[17] = xr[tr];

  // pin all loads before the selects (forced MLP)
  asm volatile("" ::: "memory");

  float o[16];
#pragma unroll
  for (int k = 0; k < 16; ++k) {
    const uint32_t d = (dw[k >> 2] >> ((k & 3) * 8)) & 3u;
    // src = t0 + k + d - 1  ->  w-index = k + d  (compile-time k, 2 cndmask)
    o[k] = (d == 0) ? w[k] : ((d == 1) ? w[k + 1] : w[k + 2]);
  }

  float* __restrict__ ob = out + ((size_t)(b * NCH + i)) * T_LEN + t0;
#pragma unroll
  for (int q = 0; q < 4; ++q) {
    f32x4 v;
    v.x = o[q * 4 + 0]; v.y = o[q * 4 + 1];
    v.z = o[q * 4 + 2]; v.w = o[q * 4 + 3];
    __builtin_nontemporal_store(v, (f32x4*)(ob + q * 4));
  }
}

extern "C" void kernel_launch(void* const* d_in, const int* in_sizes, int n_in,
                              void* d_out, int out_size, void* d_ws, size_t ws_size,
                              hipStream_t stream) {
  const float* x = (const float*)d_in[0];
  const float* probs = (const float*)d_in[1];
  float* out = (float*)d_out;

  uint8_t* dec = (uint8_t*)d_ws;                       // 16*8190 = 131040 B
  uint8_t* dbuf = (uint8_t*)d_ws + 131072;             // 16*8192 = 128 KiB

  dim3 g1((NSTEP + 255) / 256, NB);
  k_decide<<<g1, 256, 0, stream>>>(probs, dec);

  k_scan<<<NB, 256, 0, stream>>>(dec, dbuf);

  // 16 batches * 256 channels * 2 t-halves = 8192 blocks, linear sweep
  k_gather<<<NB * NCH * 2, 256, 0, stream>>>(x, dbuf, out);
}

// Round 10
// 66.105 us; speedup vs baseline: 1.5190x; 1.5190x over previous
//
#include <hip/hip_runtime.h>
#include <stdint.h>

#define T_LEN 8192
#define NSTEP 8190   // T - 2 interior samples
#define NB 16
#define NCH 256

// ---------------- threefry2x32 (exact JAX cipher) ----------------
__device__ __forceinline__ uint32_t rotl32(uint32_t v, int r) {
  return (v << r) | (v >> (32 - r));
}

__device__ __forceinline__ void tf2x32(uint32_t k0, uint32_t k1, uint32_t x0, uint32_t x1,
                                       uint32_t& o0, uint32_t& o1) {
  uint32_t ks2 = k0 ^ k1 ^ 0x1BD11BDAu;
  x0 += k0; x1 += k1;
#define RR(r) { x0 += x1; x1 = rotl32(x1, (r)); x1 ^= x0; }
  RR(13) RR(15) RR(26) RR(6)   x0 += k1;  x1 += ks2 + 1u;
  RR(17) RR(29) RR(16) RR(24)  x0 += ks2; x1 += k0 + 2u;
  RR(13) RR(15) RR(26) RR(6)   x0 += k0;  x1 += k1 + 3u;
  RR(17) RR(29) RR(16) RR(24)  x0 += k1;  x1 += ks2 + 4u;
  RR(13) RR(15) RR(26) RR(6)   x0 += ks2; x1 += k0 + 5u;
#undef RR
  o0 = x0; o1 = x1;
}

// ---------------- K1: per-step categorical decisions (VERIFIED r3) ----------
// PARTITIONABLE threefry semantics (JAX >= 0.4.36 default):
//   split(key, n)[i]          = full cipher pair threefry2x32(key, (hi32(i), lo32(i)))
//   random_bits(key,32,(m,))  = bits1 ^ bits2 of cipher(key, (0, c)), c = 0..m-1
// Record BOTH possible decisions: n (normal row), sp (special row (2,1)),
// packed as byte n | (sp<<2).
__global__ __launch_bounds__(256) void k_decide(const float* __restrict__ probs,
                                                uint8_t* __restrict__ dec) {
  int j = blockIdx.x * 256 + threadIdx.x;
  int b = blockIdx.y;
  if (j >= NSTEP) return;

  uint32_t kb0, kb1;
  tf2x32(0u, 42u, 0u, (uint32_t)b, kb0, kb1);      // split(key(42),16)[b]
  uint32_t s0, s1;
  tf2x32(kb0, kb1, 0u, (uint32_t)j, s0, s1);       // split(kb,8190)[j]

  uint32_t bits[3];
  {
    uint32_t y0, y1;
    tf2x32(s0, s1, 0u, 0u, y0, y1); bits[0] = y0 ^ y1;
    tf2x32(s0, s1, 0u, 1u, y0, y1); bits[1] = y0 ^ y1;
    tf2x32(s0, s1, 0u, 2u, y0, y1); bits[2] = y0 ^ y1;
  }

  double g[3];
#pragma unroll
  for (int c = 0; c < 3; ++c) {
    uint32_t k = bits[c] >> 9;                            // 23-bit mantissa sample
    float u = k ? (float)k * 0x1p-23f : 1.17549435e-38f;  // exact JAX uniform value
    g[c] = -log(-log((double)u));
  }

  double lp = log((double)probs[0]);
  double ls = log((double)probs[1]);
  double l1 = log((double)probs[2 * 9 + 1 * 3 + 1]);
  double l2 = log((double)probs[2 * 9 + 1 * 3 + 2]);

  double v0 = lp + g[0], v1 = ls + g[1], v2 = lp + g[2];
  int n = 0; double best = v0;
  if (v1 > best) { n = 1; best = v1; }
  if (v2 > best) { n = 2; }
  int sp = (l1 + g[1] >= l2 + g[2]) ? 1 : 2;

  dec[b * NSTEP + j] = (uint8_t)(n | (sp << 2));
}

// ---------------- K2: parallel Markov scan -> delta bytes (VERIFIED r4) ----
// State u = p2*3 + p1 in [0,9). Step: j = (u==7) ? spec : norm; u' = (u%3)*3 + j.
// Output: dbuf[b][t] = j in {0,1,2}; gather source = t + j - 1.
__device__ __forceinline__ uint64_t compose_map(uint64_t f, uint64_t g) {
  uint64_t r = 0;
#pragma unroll
  for (int st = 0; st < 9; ++st) {
    uint32_t fs = (uint32_t)((f >> (4 * st)) & 15u);
    uint32_t gs = (uint32_t)((g >> (4 * fs)) & 15u);
    r |= ((uint64_t)gs) << (4 * st);
  }
  return r;
}

__device__ __forceinline__ uint64_t shflup64(uint64_t v, int delta) {
  int lo = __shfl_up((int)(uint32_t)v, delta, 64);
  int hi = __shfl_up((int)(uint32_t)(v >> 32), delta, 64);
  return (((uint64_t)(uint32_t)hi) << 32) | (uint32_t)lo;
}

#define IDENT_MAP 0x876543210ull

__global__ __launch_bounds__(256) void k_scan(const uint8_t* __restrict__ dec,
                                              uint8_t* __restrict__ dbuf) {
  int b = blockIdx.x;
  int tid = threadIdx.x;
  int lane = tid & 63, wave = tid >> 6;
  int begin = tid * 32;
  const uint8_t* row = dec + b * NSTEP;

  // phase 1: build this chunk's 9-state map
  uint64_t M = IDENT_MAP;
#pragma unroll
  for (int t = 0; t < 32; ++t) {
    int step = begin + t;
    if (step < NSTEP) {
      int d = row[step];
      uint32_t n = d & 3u, s = (d >> 2) & 3u;
      uint64_t Mn = 0;
#pragma unroll
      for (int st = 0; st < 9; ++st) {
        uint32_t u = (uint32_t)((M >> (4 * st)) & 15u);
        uint32_t div3 = (u * 11u) >> 5;          // u/3 for u<9
        uint32_t p1 = u - 3u * div3;
        uint32_t jj = (u == 7u) ? s : n;
        Mn |= ((uint64_t)(p1 * 3u + jj)) << (4 * st);
      }
      M = Mn;
    }
  }

  // phase 2a: wave-inclusive scan
  uint64_t I = M;
#pragma unroll
  for (int off = 1; off < 64; off <<= 1) {
    uint64_t Mp = shflup64(I, off);
    uint64_t c = compose_map(Mp, I);
    I = (lane >= off) ? c : I;
  }

  __shared__ uint64_t wmap[4];
  if (lane == 63) wmap[wave] = I;
  __syncthreads();

  // phase 2b: exclusive prefix
  uint64_t W = IDENT_MAP;
  for (int w = 0; w < wave; ++w) W = compose_map(W, wmap[w]);
  uint64_t E = shflup64(I, 1);
  if (lane == 0) E = IDENT_MAP;
  uint64_t X = compose_map(W, E);

  int state = (int)((X >> (4 * 4)) & 15u);  // applied to initial chain state (1,1)=4

  // phase 3: replay chunk, emit delta bytes dbuf[b][step+1] = j
  uint8_t* orow = dbuf + b * T_LEN;
#pragma unroll
  for (int t = 0; t < 32; ++t) {
    int step = begin + t;
    if (step < NSTEP) {
      int d = row[step];
      uint32_t n = d & 3u, s = (d >> 2) & 3u;
      uint32_t jj = (state == 7) ? s : n;
      uint32_t div3 = ((uint32_t)state * 11u) >> 5;
      uint32_t p1 = (uint32_t)state - 3u * div3;
      state = (int)(p1 * 3u + jj);
      orow[step + 1] = (uint8_t)jj;
    }
  }
  if (tid == 0) { orow[0] = 1; orow[T_LEN - 1] = 1; }   // forced j=1 -> src=t
}

// ---------------- K3: grid-stride shift-select gather ----------------------
// out[b,i,t] = x[b,i,t+d-1], d in {0,1,2}. PERSISTENT-BLOCK grid-stride loop
// (the execution shape of the 7.1 TB/s fill / 6.3 TB/s copy references):
// each wave iterates 16 times; loads of iteration k+1 overlap the store
// drain of iteration k, eliminating the one-shot wave tail that r5-r8 all
// shared. Per iter: 1 uchar4 dbuf (L2-hot) + 1 float4 + 2 halo scalars +
// 1 nt float4 store. No local arrays, no asm barriers (r9 lesson: both
// force scratch / defeat the scheduler).
typedef float f32x4 __attribute__((ext_vector_type(4)));

#define GATHER_BLOCKS 2048

__global__ __launch_bounds__(256) void k_gather(const float* __restrict__ x,
                                                const uint8_t* __restrict__ dbuf,
                                                float* __restrict__ out) {
  const size_t total = (size_t)NB * NCH * (T_LEN / 4);   // 8,388,608 float4s
  const size_t stride = (size_t)GATHER_BLOCKS * 256;

  for (size_t g = (size_t)blockIdx.x * 256 + threadIdx.x; g < total; g += stride) {
    const int t4 = (int)(g & (T_LEN / 4 - 1));           // float4 index in row
    const int i  = (int)((g >> 11) & (NCH - 1));         // channel
    const int b  = (int)(g >> 19);                       // batch
    const int t0 = t4 * 4;

    const uchar4 du = *(const uchar4*)(dbuf + b * T_LEN + t0);
    const float* __restrict__ xr = x + ((size_t)(b * NCH + i)) * T_LEN;

    const float4 v = *(const float4*)(xr + t0);
    const int tl = (t0 == 0) ? 0 : t0 - 1;                    // clamped, never selected
    const int tr = (t0 + 4 >= T_LEN) ? (T_LEN - 1) : t0 + 4;  // clamped, never selected
    const float L = xr[tl];
    const float R = xr[tr];

    f32x4 o;
    o.x = (du.x == 0) ? L   : ((du.x == 1) ? v.x : v.y);
    o.y = (du.y == 0) ? v.x : ((du.y == 1) ? v.y : v.z);
    o.z = (du.z == 0) ? v.y : ((du.z == 1) ? v.z : v.w);
    o.w = (du.w == 0) ? v.z : ((du.w == 1) ? v.w : R);
    __builtin_nontemporal_store(o, (f32x4*)(out + ((size_t)(b * NCH + i)) * T_LEN + t0));
  }
}

extern "C" void kernel_launch(void* const* d_in, const int* in_sizes, int n_in,
                              void* d_out, int out_size, void* d_ws, size_t ws_size,
                              hipStream_t stream) {
  const float* x = (const float*)d_in[0];
  const float* probs = (const float*)d_in[1];
  float* out = (float*)d_out;

  uint8_t* dec = (uint8_t*)d_ws;                       // 16*8190 = 131040 B
  uint8_t* dbuf = (uint8_t*)d_ws + 131072;             // 16*8192 = 128 KiB

  dim3 g1((NSTEP + 255) / 256, NB);
  k_decide<<<g1, 256, 0, stream>>>(probs, dec);

  k_scan<<<NB, 256, 0, stream>>>(dec, dbuf);

  k_gather<<<GATHER_BLOCKS, 256, 0, stream>>>(x, dbuf, out);
}